// Round 3
// baseline (556.737 us; speedup 1.0000x reference)
//
#include <hip/hip_runtime.h>
#include <hip/hip_cooperative_groups.h>
#include <stdint.h>

namespace cg = cooperative_groups;

// Problem constants: B=128, D=512, N_ENVS=4, k = int(0.1*512*512) = 26214.
#define D_DIM   512
#define DD      262144                    // D*D
#define DD4     65536                     // DD / 4 (float4 groups)
#define B_DIM   128
#define N_ENVS  4
#define K_SEL   26214
#define BDD     33554432u                 // B*D*D
#define NSLICE  64                        // selection slices per env
#define NBLK    64                        // (fallback path) hist/gather blocks per env
#define CAP2    98304                     // max gathered pairs per env (expect ~28K)
#define CAP3    4096                      // max in-LDS pairs for final rank select (expect ~400)

typedef float nfloat4 __attribute__((ext_vector_type(4)));

// ---- workspace layout (bytes) ----
// [0,32)        thrcut[4][2]
// [64,96)       pk[4][2]            (fallback path only)
// [128,144)     cnt8[4]
// [4096,+256K)  histp[64][4][256] u32 per-block partial hists (plain stores)
// [512K,+3M)    pairs8[4][CAP2] (uint2)
#define PK_OFF      64
#define CNT_OFF     128
#define HISTP_OFF   4096
#define PAIRS_OFF   (512 * 1024)
#define PAIRS_BYTES ((size_t)N_ENVS * CAP2 * 8)
#define SEL_NEED    (PAIRS_OFF + PAIRS_BYTES)

__device__ __forceinline__ uint32_t fkey(float f) {
    uint32_t u = __float_as_uint(f);
    return (u & 0x80000000u) ? ~u : (u | 0x80000000u);
}
__device__ __forceinline__ float sigmoidf_(float x) {
    return 1.0f / (1.0f + __expf(-x));
}

// ============================================================================
// MEGA: one cooperative kernel. grid 256 x 1024 (1 block/CU, co-resident).
// Phase 1: selection byte-hist (slice/env)  +  write logits/soft planes
//          (268 MB, thrcut-independent -> overlaps the latency-bound hist).
// Phase 2: pick byte-bin P per env; gather (key,idx) pairs (keys kept in regs
//          from phase 1 -- zero re-reads).
// Phase 3: 4 blocks refine bits 16-23 + exact rank select -> thrcut.
// Phase 4: write A plane (134 MB) using thrcut.
// ============================================================================
__global__ __launch_bounds__(1024) void mega_kernel(
    const int* __restrict__ env_idx, const float* __restrict__ base,
    const float* __restrict__ deltas, uint32_t* __restrict__ histp,
    uint32_t* __restrict__ cnt8, uint2* __restrict__ pairs8,
    uint32_t* __restrict__ thrcut, float* __restrict__ out)
{
    cg::grid_group grid = cg::this_grid();
    const int bid = blockIdx.x;            // 0..255
    const int tid = threadIdx.x;           // 0..1023
    const int e   = bid & (N_ENVS - 1);    // env for selection phases
    const int s   = bid >> 2;              // slice 0..63

    __shared__ uint32_t s_h[256];
    __shared__ uint32_t s_scan[1024];
    __shared__ uint32_t s_misc[4];         // [0]=P  [1]=krem8  [2]=scan base  [3]=cnt
    __shared__ uint2    s_pairs[CAP3];     // 32 KB, phase 3 only

    const float4* b4 = (const float4*)base;
    const float4* d4 = (const float4*)(deltas + (size_t)e * DD);

    // ---------------- Phase 1a: byte-histogram of my slice ----------------
    if (tid < 256) s_h[tid] = 0;
    if (s == 0 && tid == 0) cnt8[e] = 0;
    __syncthreads();
    const int g_sel = s * 1024 + tid;                 // float4 group in [0, DD4)
    float4 bs = b4[g_sel], ds = d4[g_sel];
    uint32_t k0 = fkey(bs.x + ds.x), k1 = fkey(bs.y + ds.y);
    uint32_t k2 = fkey(bs.z + ds.z), k3 = fkey(bs.w + ds.w);
    atomicAdd(&s_h[k0 >> 24], 1u);
    atomicAdd(&s_h[k1 >> 24], 1u);
    atomicAdd(&s_h[k2 >> 24], 1u);
    atomicAdd(&s_h[k3 >> 24], 1u);
    __syncthreads();
    if (tid < 256) histp[(s * N_ENVS + e) * 256 + tid] = s_h[tid];

    // ------- Phase 1b: logits + soft planes (no thrcut dependency) -------
    // Thread owns group gq for a 32-row band h: block's h is uniform
    // (h = bid/64), so env_idx[b] is wave-uniform -> uniform switch.
    {
        const int gt = bid * 1024 + tid;              // 0..262143
        const int gq = gt & (DD4 - 1);
        const int h  = gt >> 16;                      // 0..3
        float4 bq = b4[gq];
        nfloat4 lgv[N_ENVS], sgv[N_ENVS];
        #pragma unroll
        for (int e2 = 0; e2 < N_ENVS; ++e2) {
            float4 dq = ((const float4*)(deltas + (size_t)e2 * DD))[gq];
            nfloat4 lg = { bq.x + dq.x, bq.y + dq.y, bq.z + dq.z, bq.w + dq.w };
            lgv[e2] = lg;
            sgv[e2] = nfloat4{ sigmoidf_(lg.x), sigmoidf_(lg.y),
                               sigmoidf_(lg.z), sigmoidf_(lg.w) };
        }
        nfloat4* o0 = (nfloat4*)out + gq;
        #pragma unroll 4
        for (int bb = 0; bb < 32; ++bb) {
            int b = h * 32 + bb;
            int ee = env_idx[b];                      // wave-uniform
            nfloat4* o = o0 + (size_t)b * DD4;
            switch (ee) {
            case 0:  o[BDD/4] = lgv[0]; o[2*(BDD/4)] = sgv[0]; break;
            case 1:  o[BDD/4] = lgv[1]; o[2*(BDD/4)] = sgv[1]; break;
            case 2:  o[BDD/4] = lgv[2]; o[2*(BDD/4)] = sgv[2]; break;
            default: o[BDD/4] = lgv[3]; o[2*(BDD/4)] = sgv[3]; break;
            }
        }
    }
    grid.sync();

    // ---------------- Phase 2: pick P per env; gather pairs ----------------
    if (tid < 256) {
        uint32_t sum = 0;
        #pragma unroll 8
        for (int j = 0; j < NSLICE; ++j)
            sum += histp[(j * N_ENVS + e) * 256 + tid];
        s_h[tid] = sum;
    }
    __syncthreads();
    if (tid == 0) {
        uint32_t cum = 0;
        for (int b = 255; b >= 0; --b) {
            uint32_t c = s_h[b];
            if (cum + c >= (uint32_t)K_SEL) {
                s_misc[0] = (uint32_t)b;
                s_misc[1] = (uint32_t)K_SEL - cum;    // krem8 >= 1
                break;
            }
            cum += c;
        }
    }
    __syncthreads();
    const uint32_t P = s_misc[0];
    uint32_t m = ((k0 >> 24) == P) + ((k1 >> 24) == P)
               + ((k2 >> 24) == P) + ((k3 >> 24) == P);
    s_scan[tid] = m;
    __syncthreads();
    #pragma unroll
    for (int off = 1; off < 1024; off <<= 1) {
        uint32_t v = (tid >= off) ? s_scan[tid - off] : 0u;
        __syncthreads();
        s_scan[tid] += v;
        __syncthreads();
    }
    uint32_t excl = s_scan[tid] - m;
    if (tid == 1023) s_misc[2] = atomicAdd(&cnt8[e], s_scan[1023]);
    __syncthreads();
    {
        uint32_t pos = s_misc[2] + excl;
        uint2* pp = pairs8 + (size_t)e * CAP2;
        uint32_t kk[4] = { k0, k1, k2, k3 };
        #pragma unroll
        for (int j = 0; j < 4; ++j) {
            if ((kk[j] >> 24) == P) {
                if (pos < CAP2) pp[pos] = make_uint2(kk[j], (uint32_t)(g_sel * 4 + j));
                ++pos;
            }
        }
    }
    grid.sync();

    // ------- Phase 3: 4 blocks (e==bid, s==0 so krem8 is in s_misc[1]) -----
    if (bid < N_ENVS) {
        const uint2* pp = pairs8 + (size_t)bid * CAP2;
        uint32_t M = cnt8[bid]; if (M > CAP2) M = CAP2;
        uint32_t krem8 = s_misc[1];
        if (tid < 256) s_h[tid] = 0;
        if (tid == 0) s_misc[3] = 0;
        __syncthreads();
        for (uint32_t j = tid; j < M; j += 1024)
            atomicAdd(&s_h[(pp[j].x >> 16) & 255u], 1u);
        __syncthreads();
        if (tid == 0) {
            uint32_t cum = 0;
            for (int b = 255; b >= 0; --b) {
                uint32_t c = s_h[b];
                if (cum + c >= krem8) { s_misc[0] = (uint32_t)b; s_misc[1] = krem8 - cum; break; }
                cum += c;
            }
        }
        __syncthreads();
        uint32_t b16 = s_misc[0];
        for (uint32_t j = tid; j < M; j += 1024) {
            uint2 p = pp[j];
            if (((p.x >> 16) & 255u) == b16) {
                uint32_t pos = atomicAdd(&s_misc[3], 1u);
                if (pos < CAP3) s_pairs[pos] = p;
            }
        }
        __syncthreads();
        uint32_t M2 = s_misc[3]; if (M2 > CAP3) M2 = CAP3;
        uint32_t target = s_misc[1] - 1;              // 0-based rank
        for (uint32_t j = tid; j < M2; j += 1024) {
            uint2 me = s_pairs[j];
            uint32_t rank = 0;
            for (uint32_t l = 0; l < M2; ++l) {
                uint2 o = s_pairs[l];
                rank += (o.x > me.x) || (o.x == me.x && o.y < me.y);
            }
            if (rank == target) {
                thrcut[2 * bid + 0] = me.x;
                thrcut[2 * bid + 1] = me.y;
            }
        }
        __threadfence();
    }
    grid.sync();

    // ---------------- Phase 4: A plane (needs thrcut) ----------------
    {
        const int gt = bid * 1024 + tid;
        const int gq = gt & (DD4 - 1);
        const int h  = gt >> 16;
        const uint32_t i0 = (uint32_t)gq * 4u;
        float4 bq = b4[gq];
        nfloat4 avv[N_ENVS];
        #pragma unroll
        for (int e2 = 0; e2 < N_ENVS; ++e2) {
            float4 dq = ((const float4*)(deltas + (size_t)e2 * DD))[gq];
            uint32_t T = thrcut[2 * e2], C = thrcut[2 * e2 + 1];
            nfloat4 lg = { bq.x + dq.x, bq.y + dq.y, bq.z + dq.z, bq.w + dq.w };
            nfloat4 sg = { sigmoidf_(lg.x), sigmoidf_(lg.y),
                           sigmoidf_(lg.z), sigmoidf_(lg.w) };
            uint32_t kx = fkey(lg.x), ky = fkey(lg.y);
            uint32_t kz = fkey(lg.z), kw = fkey(lg.w);
            nfloat4 av;
            av.x = (kx > T || (kx == T && i0 + 0u <= C)) ? sg.x : 0.0f;
            av.y = (ky > T || (ky == T && i0 + 1u <= C)) ? sg.y : 0.0f;
            av.z = (kz > T || (kz == T && i0 + 2u <= C)) ? sg.z : 0.0f;
            av.w = (kw > T || (kw == T && i0 + 3u <= C)) ? sg.w : 0.0f;
            avv[e2] = av;
        }
        nfloat4* o0 = (nfloat4*)out + gq;
        #pragma unroll 4
        for (int bb = 0; bb < 32; ++bb) {
            int b = h * 32 + bb;
            int ee = env_idx[b];
            nfloat4* o = o0 + (size_t)b * DD4;
            switch (ee) {
            case 0:  o[0] = avv[0]; break;
            case 1:  o[0] = avv[1]; break;
            case 2:  o[0] = avv[2]; break;
            default: o[0] = avv[3]; break;
            }
        }
    }
}

// ============================================================================
// Fallback chain (verified round-2 kernels) — used if cooperative launch is
// unavailable or workspace is too small.
// ============================================================================
__global__ __launch_bounds__(256) void hist8_kernel(
    const float* __restrict__ base, const float* __restrict__ deltas,
    uint32_t* __restrict__ histp, uint32_t* __restrict__ cnt8)
{
    int e = blockIdx.y;
    const float4* b4 = (const float4*)base;
    const float4* d4 = (const float4*)(deltas + (size_t)e * DD);
    __shared__ uint32_t s_h[256];
    int tid = threadIdx.x;
    s_h[tid] = 0;
    if (blockIdx.x == 0 && tid == 0) cnt8[e] = 0;
    __syncthreads();
    int g0 = blockIdx.x * 256 + tid;
    #pragma unroll
    for (int r = 0; r < 4; ++r) {
        int g = g0 + r * 16384;
        float4 bv = b4[g], dv = d4[g];
        atomicAdd(&s_h[fkey(bv.x + dv.x) >> 24], 1u);
        atomicAdd(&s_h[fkey(bv.y + dv.y) >> 24], 1u);
        atomicAdd(&s_h[fkey(bv.z + dv.z) >> 24], 1u);
        atomicAdd(&s_h[fkey(bv.w + dv.w) >> 24], 1u);
    }
    __syncthreads();
    histp[(blockIdx.x * N_ENVS + e) * 256 + tid] = s_h[tid];
}

__global__ __launch_bounds__(256) void gather8_kernel(
    const float* __restrict__ base, const float* __restrict__ deltas,
    const uint32_t* __restrict__ histp, uint32_t* __restrict__ pk,
    uint32_t* __restrict__ cnt8, uint2* __restrict__ pairs8)
{
    int e = blockIdx.y;
    const float4* b4 = (const float4*)base;
    const float4* d4 = (const float4*)(deltas + (size_t)e * DD);
    uint2* pp = pairs8 + (size_t)e * CAP2;
    __shared__ uint32_t s_h[256];
    __shared__ uint32_t s_scan[256];
    __shared__ uint32_t s_P, s_base;
    int tid = threadIdx.x;
    uint32_t sum = 0;
    #pragma unroll 8
    for (int j = 0; j < NBLK; ++j)
        sum += histp[(j * N_ENVS + e) * 256 + tid];
    s_h[tid] = sum;
    __syncthreads();
    if (tid == 0) {
        uint32_t cum = 0;
        for (int b = 255; b >= 0; --b) {
            uint32_t c = s_h[b];
            if (cum + c >= (uint32_t)K_SEL) {
                s_P = (uint32_t)b;
                if (blockIdx.x == 0) {
                    pk[2 * e + 0] = (uint32_t)b;
                    pk[2 * e + 1] = (uint32_t)K_SEL - cum;
                }
                break;
            }
            cum += c;
        }
    }
    __syncthreads();
    uint32_t P = s_P;
    int g0 = blockIdx.x * 256 + tid;
    uint32_t keys[16];
    uint32_t m = 0;
    #pragma unroll
    for (int r = 0; r < 4; ++r) {
        int g = g0 + r * 16384;
        float4 bv = b4[g], dv = d4[g];
        uint32_t c0 = fkey(bv.x + dv.x), c1 = fkey(bv.y + dv.y);
        uint32_t c2 = fkey(bv.z + dv.z), c3 = fkey(bv.w + dv.w);
        keys[r*4+0]=c0; keys[r*4+1]=c1; keys[r*4+2]=c2; keys[r*4+3]=c3;
        m += ((c0>>24)==P) + ((c1>>24)==P) + ((c2>>24)==P) + ((c3>>24)==P);
    }
    s_scan[tid] = m;
    __syncthreads();
    #pragma unroll
    for (int off = 1; off < 256; off <<= 1) {
        uint32_t v = (tid >= off) ? s_scan[tid - off] : 0u;
        __syncthreads();
        s_scan[tid] += v;
        __syncthreads();
    }
    uint32_t excl = s_scan[tid] - m;
    if (tid == 255) s_base = atomicAdd(&cnt8[e], s_scan[255]);
    __syncthreads();
    uint32_t pos = s_base + excl;
    #pragma unroll
    for (int r = 0; r < 4; ++r) {
        int g = g0 + r * 16384;
        #pragma unroll
        for (int j = 0; j < 4; ++j) {
            uint32_t key = keys[r * 4 + j];
            if ((key >> 24) == P) {
                if (pos < CAP2) pp[pos] = make_uint2(key, (uint32_t)(g * 4 + j));
                ++pos;
            }
        }
    }
}

__global__ __launch_bounds__(1024) void select2_kernel(
    const uint32_t* __restrict__ pk, const uint32_t* __restrict__ cnt8,
    const uint2* __restrict__ pairs8, uint32_t* __restrict__ thrcut)
{
    int e = blockIdx.x;
    const uint2* pp = pairs8 + (size_t)e * CAP2;
    uint32_t M = cnt8[e]; if (M > CAP2) M = CAP2;
    uint32_t krem8 = pk[2 * e + 1];
    __shared__ uint32_t s_h16[256];
    __shared__ uint2    s_pairs[CAP3];
    __shared__ uint32_t s_b16, s_krem16, s_cnt;
    int tid = threadIdx.x;
    if (tid < 256) s_h16[tid] = 0;
    if (tid == 0) s_cnt = 0;
    __syncthreads();
    for (uint32_t j = tid; j < M; j += 1024)
        atomicAdd(&s_h16[(pp[j].x >> 16) & 255u], 1u);
    __syncthreads();
    if (tid == 0) {
        uint32_t cum = 0;
        for (int b = 255; b >= 0; --b) {
            uint32_t c = s_h16[b];
            if (cum + c >= krem8) { s_b16 = (uint32_t)b; s_krem16 = krem8 - cum; break; }
            cum += c;
        }
    }
    __syncthreads();
    uint32_t b16 = s_b16;
    for (uint32_t j = tid; j < M; j += 1024) {
        uint2 p = pp[j];
        if (((p.x >> 16) & 255u) == b16) {
            uint32_t pos = atomicAdd(&s_cnt, 1u);
            if (pos < CAP3) s_pairs[pos] = p;
        }
    }
    __syncthreads();
    uint32_t M2 = s_cnt; if (M2 > CAP3) M2 = CAP3;
    uint32_t target = s_krem16 - 1;
    for (uint32_t j = tid; j < M2; j += 1024) {
        uint2 me = s_pairs[j];
        uint32_t rank = 0;
        for (uint32_t l = 0; l < M2; ++l) {
            uint2 o = s_pairs[l];
            rank += (o.x > me.x) || (o.x == me.x && o.y < me.y);
        }
        if (rank == target) {
            thrcut[2 * e + 0] = me.x;
            thrcut[2 * e + 1] = me.y;
        }
    }
}

__global__ __launch_bounds__(256) void write_bcast_kernel(
    const int* __restrict__ env_idx, const float* __restrict__ base,
    const float* __restrict__ deltas, const uint32_t* __restrict__ thrcut,
    float* __restrict__ out)
{
    int g = blockIdx.x * 256 + threadIdx.x;
    uint32_t i0 = (uint32_t)g * 4u;
    float4 bv = ((const float4*)base)[g];
    nfloat4 lgv[N_ENVS], sgv[N_ENVS], avv[N_ENVS];
    #pragma unroll
    for (int e = 0; e < N_ENVS; ++e) {
        float4 dv = ((const float4*)(deltas + (size_t)e * DD))[g];
        uint32_t T = thrcut[2 * e], C = thrcut[2 * e + 1];
        nfloat4 lg = { bv.x + dv.x, bv.y + dv.y, bv.z + dv.z, bv.w + dv.w };
        nfloat4 sg = { sigmoidf_(lg.x), sigmoidf_(lg.y),
                       sigmoidf_(lg.z), sigmoidf_(lg.w) };
        uint32_t kx = fkey(lg.x), ky = fkey(lg.y);
        uint32_t kz = fkey(lg.z), kw = fkey(lg.w);
        nfloat4 av;
        av.x = (kx > T || (kx == T && i0 + 0u <= C)) ? sg.x : 0.0f;
        av.y = (ky > T || (ky == T && i0 + 1u <= C)) ? sg.y : 0.0f;
        av.z = (kz > T || (kz == T && i0 + 2u <= C)) ? sg.z : 0.0f;
        av.w = (kw > T || (kw == T && i0 + 3u <= C)) ? sg.w : 0.0f;
        lgv[e] = lg; sgv[e] = sg; avv[e] = av;
    }
    const int ROWS = B_DIM / 8;
    int b0 = blockIdx.y * ROWS;
    nfloat4* o0 = (nfloat4*)out + g;
    #pragma unroll 4
    for (int bb = 0; bb < ROWS; ++bb) {
        int b = b0 + bb;
        int e = env_idx[b];
        nfloat4* o = o0 + (size_t)b * DD4;
        switch (e) {
        case 0: o[0] = avv[0]; o[BDD/4] = lgv[0]; o[2*(BDD/4)] = sgv[0]; break;
        case 1: o[0] = avv[1]; o[BDD/4] = lgv[1]; o[2*(BDD/4)] = sgv[1]; break;
        case 2: o[0] = avv[2]; o[BDD/4] = lgv[2]; o[2*(BDD/4)] = sgv[2]; break;
        default: o[0] = avv[3]; o[BDD/4] = lgv[3]; o[2*(BDD/4)] = sgv[3]; break;
        }
    }
}

extern "C" void kernel_launch(void* const* d_in, const int* in_sizes, int n_in,
                              void* d_out, int out_size, void* d_ws, size_t ws_size,
                              hipStream_t stream) {
    // inputs: 0=z_s (unused), 1=env_idx (int32), 2=A_base (f32), 3=A_deltas (f32)
    const int*   env_idx  = (const int*)d_in[1];
    const float* A_base   = (const float*)d_in[2];
    const float* A_deltas = (const float*)d_in[3];
    float* out = (float*)d_out;

    uint32_t* thrcut = (uint32_t*)d_ws;

    bool ws_ok = (ws_size >= SEL_NEED);
    char* scratch;
    if (ws_ok) {
        scratch = (char*)d_ws;
    } else {
        // Carve selection scratch from d_out's tail (fallback chain only --
        // in the mega kernel phase 1b would clobber it).
        size_t out_bytes = (size_t)out_size * sizeof(float);
        scratch = (char*)d_out + ((out_bytes - SEL_NEED) & ~(size_t)255);
    }
    uint32_t* pk     = (uint32_t*)(scratch + PK_OFF);
    uint32_t* cnt8   = (uint32_t*)(scratch + CNT_OFF);
    uint32_t* histp  = (uint32_t*)(scratch + HISTP_OFF);
    uint2*    pairs8 = (uint2*)   (scratch + PAIRS_OFF);

    bool launched = false;
    if (ws_ok) {
        void* args[] = { (void*)&env_idx, (void*)&A_base, (void*)&A_deltas,
                         (void*)&histp, (void*)&cnt8, (void*)&pairs8,
                         (void*)&thrcut, (void*)&out };
        hipError_t err = hipLaunchCooperativeKernel(
            (const void*)mega_kernel, dim3(NSLICE * N_ENVS), dim3(1024),
            args, 0, stream);
        launched = (err == hipSuccess);
        if (!launched) (void)hipGetLastError();       // clear sticky error
    }
    if (!launched) {
        hist8_kernel  <<<dim3(NBLK, N_ENVS), 256, 0, stream>>>(A_base, A_deltas,
                                                               histp, cnt8);
        gather8_kernel<<<dim3(NBLK, N_ENVS), 256, 0, stream>>>(A_base, A_deltas,
                                                               histp, pk, cnt8, pairs8);
        select2_kernel<<<N_ENVS, 1024, 0, stream>>>(pk, cnt8, pairs8, thrcut);
        write_bcast_kernel<<<dim3(DD4 / 256, 8), 256, 0, stream>>>(
            env_idx, A_base, A_deltas, thrcut, out);
    }
}